// Round 3
// baseline (328.645 us; speedup 1.0000x reference)
//
#include <hip/hip_runtime.h>
#include <hip/hip_bf16.h>

#define NN 32768
#define DEG 32
#define FF 128
#define OO 128
#define MB 32   // nodes per block

typedef __attribute__((ext_vector_type(8))) short bfrag;   // 8 bf16 (MFMA A/B operand)
typedef __attribute__((ext_vector_type(4))) float f32x4;   // MFMA C/D

#define K1 1.4426950408889634f

// cheap fp32->bf16: round-half-up == RNE except exact ties (prob 2^-16)
__device__ __forceinline__ unsigned short b16(float x) {
    unsigned u = __float_as_uint(x) + 0x8000u;
    return (unsigned short)(u >> 16);
}
__device__ __forceinline__ bfrag pack8(float4 a, float4 b) {
    bfrag r;
    r[0] = (short)b16(a.x); r[1] = (short)b16(a.y); r[2] = (short)b16(a.z); r[3] = (short)b16(a.w);
    r[4] = (short)b16(b.x); r[5] = (short)b16(b.y); r[6] = (short)b16(b.z); r[7] = (short)b16(b.w);
    return r;
}

__device__ __forceinline__ float fsig(float x, float nb) {
    // sigmoid(x+b) = rcp(1 + exp2(-K1*x + nb)), nb = -K1*b
    return __builtin_amdgcn_rcpf(1.0f + __builtin_amdgcn_exp2f(fmaf(-K1, x, nb)));
}
__device__ __forceinline__ float ftanh_b(float x, float pb) {
    // tanh(x+b) = 1 - 2*rcp(1 + exp2(2*K1*x + pb)), pb = 2*K1*b
    return fmaf(-2.0f, __builtin_amdgcn_rcpf(1.0f + __builtin_amdgcn_exp2f(fmaf(2.0f * K1, x, pb))), 1.0f);
}
__device__ __forceinline__ float ftanh(float x) {
    return fmaf(-2.0f, __builtin_amdgcn_rcpf(1.0f + __builtin_amdgcn_exp2f(2.0f * K1 * x)), 1.0f);
}

// -------- prep: weights/biases to bf16 (fold 1/deg into W2, combine biases) --------
__global__ void prep_weights(const float* __restrict__ wih, const float* __restrict__ whh,
                             const float* __restrict__ b_ih, const float* __restrict__ b_hh,
                             const float* __restrict__ w1, const float* __restrict__ b1,
                             const float* __restrict__ w2, const float* __restrict__ b2,
                             short* __restrict__ wihb, short* __restrict__ whhb,
                             short* __restrict__ w1b, short* __restrict__ w2b,
                             float* __restrict__ biasg, float* __restrict__ biaso)
{
    int i = blockIdx.x * blockDim.x + threadIdx.x;
    if (i < 512 * 128) { wihb[i] = (short)b16(wih[i]); whhb[i] = (short)b16(whh[i]); }
    if (i < 128 * 128) { w1b[i] = (short)b16(w1[i]); w2b[i] = (short)b16(w2[i] * 0.03125f); }
    if (i < 512) biasg[i] = b_ih[i] + b_hh[i];
    if (i < 128) biaso[i] = b1[i] + b2[i];
}

// -------- prep: feat fp32 -> bf16 (8 elements / thread) --------
__global__ void prep_feat(const float* __restrict__ f, short* __restrict__ fb) {
    int i = blockIdx.x * blockDim.x + threadIdx.x;       // 524288 threads
    const float4* p = reinterpret_cast<const float4*>(f) + (size_t)i * 2;
    float4 a = p[0], b = p[1];
    *reinterpret_cast<bfrag*>(fb + (size_t)i * 8) = pack8(a, b);
}

template<bool BF16F>
__device__ __forceinline__ bfrag load_row8(const float* __restrict__ ff, const short* __restrict__ fb,
                                           int node, int cs) {
    if (BF16F) {
        return *reinterpret_cast<const bfrag*>(fb + node * FF + cs * 8);
    } else {
        const float4* p = reinterpret_cast<const float4*>(ff + node * FF + cs * 8);
        return pack8(p[0], p[1]);
    }
}

// 32 nodes/block, 8 waves. Wave w owns hidden/output cols [16w,16w+16).
// Weights live in (unified VGPR/AGPR) registers for the whole kernel.
// Wave-parity rt-stagger: even waves process rt0 first, odd waves rt1 first, so
// on each SIMD one wave is in its MFMA cluster while the sibling runs the
// activation (trans/VALU) phase. s_setprio(1) biases issue toward the MFMA wave.
template<bool BF16F>
__global__ __launch_bounds__(512, 2)
void sage_lstm_kernel(const float* __restrict__ featf, const short* __restrict__ featb,
                      const int* __restrict__ nidx,
                      const short* __restrict__ wihb, const short* __restrict__ whhb,
                      const short* __restrict__ w1b, const short* __restrict__ w2b,
                      const float* __restrict__ biasg, const float* __restrict__ biaso,
                      float* __restrict__ out)
{
    __shared__ short xbuf[2][MB * 128];   // x_t tile, bf16, XOR-swizzled (ping-pong)
    __shared__ short hbuf[2][MB * 128];   // h tile, bf16, XOR-swizzled (ping-pong)
    __shared__ int   idx_s[MB * DEG];     // 32 nodes x 32 neighbor indices

    const int tid  = (int)threadIdx.x;
    const int lane = tid & 63;
    const int wave = tid >> 6;                    // 0..7
    const int n0   = (int)blockIdx.x * MB;

    const int srow = tid >> 4;                    // staging row 0..31
    const int cs   = tid & 15;                    // staging 8-elem column group

    idx_s[tid]       = nidx[n0 * DEG + tid];
    idx_s[512 + tid] = nidx[n0 * DEG + 512 + tid];
    {   bfrag z; for (int j = 0; j < 8; ++j) z[j] = 0;
        reinterpret_cast<bfrag*>(hbuf[0])[tid] = z; }

    // ---- weight B-fragments: lane holds 8 contiguous k for its column ----
    const int colw = wave * 16 + (lane & 15);
    bfrag wih[4][4], whh[4][4];
#pragma unroll
    for (int g = 0; g < 4; ++g) {
        const short* pih = wihb + (g * 128 + colw) * FF + (lane >> 4) * 8;
        const short* phh = whhb + (g * 128 + colw) * FF + (lane >> 4) * 8;
#pragma unroll
        for (int kt = 0; kt < 4; ++kt) {
            wih[g][kt] = *reinterpret_cast<const bfrag*>(pih + kt * 32);
            whh[g][kt] = *reinterpret_cast<const bfrag*>(phh + kt * 32);
        }
    }
    const float nbi = -K1 * biasg[colw];
    const float nbf = -K1 * biasg[128 + colw];
    const float pbg = 2.0f * K1 * biasg[256 + colw];
    const float nbo = -K1 * biasg[384 + colw];

    __syncthreads();   // idx_s + hbuf[0] zeros visible

    // ---- stage x_0 ----
    {
        bfrag v = load_row8<BF16F>(featf, featb, idx_s[srow * DEG], cs);
        int sb = (srow * 256 + cs * 16) ^ ((srow & 7) << 4);
        *reinterpret_cast<bfrag*>(reinterpret_cast<char*>(xbuf[0]) + sb) = v;
    }
    __syncthreads();

    const int arow = lane & 15;
    const int asub = (lane >> 4) * 16;
    const int hr0  = (lane >> 4) * 4;
    const int par  = wave & 1;                    // stagger parity
    f32x4 cs0 = {0.f, 0.f, 0.f, 0.f};
    f32x4 cs1 = {0.f, 0.f, 0.f, 0.f};

    for (int t = 0; t < DEG; ++t) {
        const int cur = t & 1;
        char* xcur = reinterpret_cast<char*>(xbuf[cur]);
        char* hcur = reinterpret_cast<char*>(hbuf[cur]);
        char* xnxt = reinterpret_cast<char*>(xbuf[cur ^ 1]);
        char* hnxt = reinterpret_cast<char*>(hbuf[cur ^ 1]);

        // issue next gather early; lands at end of step under compute
        bfrag pre;
        if (t < DEG - 1) pre = load_row8<BF16F>(featf, featb, idx_s[srow * DEG + t + 1], cs);

        auto do_rt = [&](int rt, f32x4& cst) {
            const int rowr = rt * 16 + arow;
            const int sw   = (rowr & 7) << 4;
            bfrag xa[4], ha[4];
#pragma unroll
            for (int kt = 0; kt < 4; ++kt) {
                int byte = (rowr * 256 + kt * 64 + asub) ^ sw;
                xa[kt] = *reinterpret_cast<const bfrag*>(xcur + byte);
                ha[kt] = *reinterpret_cast<const bfrag*>(hcur + byte);
            }
            f32x4 gi = {0,0,0,0}, gf = {0,0,0,0}, gg = {0,0,0,0}, go = {0,0,0,0};
            __builtin_amdgcn_s_setprio(1);
#pragma unroll
            for (int kt = 0; kt < 4; ++kt) {
                gi = __builtin_amdgcn_mfma_f32_16x16x32_bf16(xa[kt], wih[0][kt], gi, 0, 0, 0);
                gf = __builtin_amdgcn_mfma_f32_16x16x32_bf16(xa[kt], wih[1][kt], gf, 0, 0, 0);
                gg = __builtin_amdgcn_mfma_f32_16x16x32_bf16(xa[kt], wih[2][kt], gg, 0, 0, 0);
                go = __builtin_amdgcn_mfma_f32_16x16x32_bf16(xa[kt], wih[3][kt], go, 0, 0, 0);
            }
#pragma unroll
            for (int kt = 0; kt < 4; ++kt) {
                gi = __builtin_amdgcn_mfma_f32_16x16x32_bf16(ha[kt], whh[0][kt], gi, 0, 0, 0);
                gf = __builtin_amdgcn_mfma_f32_16x16x32_bf16(ha[kt], whh[1][kt], gf, 0, 0, 0);
                gg = __builtin_amdgcn_mfma_f32_16x16x32_bf16(ha[kt], whh[2][kt], gg, 0, 0, 0);
                go = __builtin_amdgcn_mfma_f32_16x16x32_bf16(ha[kt], whh[3][kt], go, 0, 0, 0);
            }
            __builtin_amdgcn_s_setprio(0);
#pragma unroll
            for (int r = 0; r < 4; ++r) {
                float iv = fsig(gi[r], nbi);
                float fv = fsig(gf[r], nbf);
                float gv = ftanh_b(gg[r], pbg);
                float ov = fsig(go[r], nbo);
                float c  = fmaf(fv, cst[r], iv * gv);
                cst[r] = c;
                float h  = ov * ftanh(c);
                int hrow = rt * 16 + hr0 + r;
                int hb   = (hrow * 256 + colw * 2) ^ ((hrow & 7) << 4);
                *reinterpret_cast<unsigned short*>(hnxt + hb) = b16(h);
            }
        };

        if (par == 0) { do_rt(0, cs0); do_rt(1, cs1); }
        else          { do_rt(1, cs1); do_rt(0, cs0); }

        if (t < DEG - 1) {
            int sb = (srow * 256 + cs * 16) ^ ((srow & 7) << 4);
            *reinterpret_cast<bfrag*>(xnxt + sb) = pre;
        }
        __syncthreads();
    }

    // ---- epilogue: out = feat@W1^T + (h/32)@W2^T + (b1+b2); h_final in hbuf[0] ----
    {
        bfrag v = load_row8<BF16F>(featf, featb, n0 + srow, cs);
        int sb = (srow * 256 + cs * 16) ^ ((srow & 7) << 4);
        *reinterpret_cast<bfrag*>(reinterpret_cast<char*>(xbuf[0]) + sb) = v;
    }
    __syncthreads();

    bfrag w1f[4], w2f[4];
#pragma unroll
    for (int kt = 0; kt < 4; ++kt) {
        w1f[kt] = *reinterpret_cast<const bfrag*>(w1b + colw * FF + kt * 32 + (lane >> 4) * 8);
        w2f[kt] = *reinterpret_cast<const bfrag*>(w2b + colw * FF + kt * 32 + (lane >> 4) * 8);
    }
    const float bb = biaso[colw];
#pragma unroll
    for (int rt = 0; rt < 2; ++rt) {
        const int rowr = rt * 16 + arow;
        const int sw   = (rowr & 7) << 4;
        bfrag fa[4], hfa[4];
#pragma unroll
        for (int kt = 0; kt < 4; ++kt) {
            int byte = (rowr * 256 + kt * 64 + asub) ^ sw;
            fa[kt]  = *reinterpret_cast<const bfrag*>(reinterpret_cast<char*>(xbuf[0]) + byte);
            hfa[kt] = *reinterpret_cast<const bfrag*>(reinterpret_cast<char*>(hbuf[0]) + byte);
        }
        f32x4 acc = {0.f, 0.f, 0.f, 0.f};
#pragma unroll
        for (int kt = 0; kt < 4; ++kt) {
            acc = __builtin_amdgcn_mfma_f32_16x16x32_bf16(fa[kt],  w1f[kt], acc, 0, 0, 0);
            acc = __builtin_amdgcn_mfma_f32_16x16x32_bf16(hfa[kt], w2f[kt], acc, 0, 0, 0);
        }
#pragma unroll
        for (int r = 0; r < 4; ++r) {
            int orow = n0 + rt * 16 + hr0 + r;
            out[orow * OO + colw] = acc[r] + bb;
        }
    }
}

extern "C" void kernel_launch(void* const* d_in, const int* in_sizes, int n_in,
                              void* d_out, int out_size, void* d_ws, size_t ws_size,
                              hipStream_t stream)
{
    const float* feat = (const float*)d_in[0];
    const int*   nidx = (const int*)d_in[1];
    const float* W_ih = (const float*)d_in[2];
    const float* W_hh = (const float*)d_in[3];
    const float* b_ih = (const float*)d_in[4];
    const float* b_hh = (const float*)d_in[5];
    const float* W1   = (const float*)d_in[6];
    const float* b1   = (const float*)d_in[7];
    const float* W2   = (const float*)d_in[8];
    const float* b2   = (const float*)d_in[9];
    float* out = (float*)d_out;

    char* ws = (char*)d_ws;
    short* wihb  = (short*)(ws);             // 131072 B
    short* whhb  = (short*)(ws + 131072);    // 131072 B
    short* w1b   = (short*)(ws + 262144);    // 32768 B
    short* w2b   = (short*)(ws + 294912);    // 32768 B
    float* biasg = (float*)(ws + 327680);    // 2048 B
    float* biaso = (float*)(ws + 329728);    // 512 B
    short* featb = (short*)(ws + 330240);    // 8388608 B (16B-aligned)

    const size_t need = 330240 + (size_t)NN * FF * 2;
    const bool bf = ws_size >= need;

    prep_weights<<<256, 256, 0, stream>>>(W_ih, W_hh, b_ih, b_hh, W1, b1, W2, b2,
                                          wihb, whhb, w1b, w2b, biasg, biaso);
    if (bf) {
        prep_feat<<<2048, 256, 0, stream>>>(feat, featb);
        sage_lstm_kernel<true><<<NN / MB, 512, 0, stream>>>(feat, featb, nidx, wihb, whhb,
                                                            w1b, w2b, biasg, biaso, out);
    } else {
        sage_lstm_kernel<false><<<NN / MB, 512, 0, stream>>>(feat, featb, nidx, wihb, whhb,
                                                             w1b, w2b, biasg, biaso, out);
    }
}

// Round 4
// 305.942 us; speedup vs baseline: 1.0742x; 1.0742x over previous
//
#include <hip/hip_runtime.h>
#include <hip/hip_bf16.h>

#define NN 32768
#define DEG 32
#define FF 128
#define OO 128
#define MB 32   // nodes per block

typedef __attribute__((ext_vector_type(8))) short bfrag;   // 8 bf16 (MFMA A/B operand)
typedef __attribute__((ext_vector_type(4))) float f32x4;   // MFMA C/D

#define K1 1.4426950408889634f

// cheap fp32->bf16: round-half-up == RNE except exact ties (prob 2^-16)
__device__ __forceinline__ unsigned short b16(float x) {
    unsigned u = __float_as_uint(x) + 0x8000u;
    return (unsigned short)(u >> 16);
}
__device__ __forceinline__ bfrag pack8(float4 a, float4 b) {
    bfrag r;
    r[0] = (short)b16(a.x); r[1] = (short)b16(a.y); r[2] = (short)b16(a.z); r[3] = (short)b16(a.w);
    r[4] = (short)b16(b.x); r[5] = (short)b16(b.y); r[6] = (short)b16(b.z); r[7] = (short)b16(b.w);
    return r;
}

// bias is pre-added into the gate value (folded into MFMA C-init)
__device__ __forceinline__ float fsig(float x) {
    return __builtin_amdgcn_rcpf(1.0f + __builtin_amdgcn_exp2f(-K1 * x));
}
__device__ __forceinline__ float ftanh(float x) {
    return fmaf(-2.0f, __builtin_amdgcn_rcpf(1.0f + __builtin_amdgcn_exp2f(2.0f * K1 * x)), 1.0f);
}

// -------- prep: weights/biases to bf16 (fold 1/deg into W2, combine biases) --------
__global__ void prep_weights(const float* __restrict__ wih, const float* __restrict__ whh,
                             const float* __restrict__ b_ih, const float* __restrict__ b_hh,
                             const float* __restrict__ w1, const float* __restrict__ b1,
                             const float* __restrict__ w2, const float* __restrict__ b2,
                             short* __restrict__ wihb, short* __restrict__ whhb,
                             short* __restrict__ w1b, short* __restrict__ w2b,
                             float* __restrict__ biasg, float* __restrict__ biaso)
{
    int i = blockIdx.x * blockDim.x + threadIdx.x;
    if (i < 512 * 128) { wihb[i] = (short)b16(wih[i]); whhb[i] = (short)b16(whh[i]); }
    if (i < 128 * 128) { w1b[i] = (short)b16(w1[i]); w2b[i] = (short)b16(w2[i] * 0.03125f); }
    if (i < 512) biasg[i] = b_ih[i] + b_hh[i];
    if (i < 128) biaso[i] = b1[i] + b2[i];
}

// -------- prep: feat fp32 -> bf16 (8 elements / thread) --------
__global__ void prep_feat(const float* __restrict__ f, short* __restrict__ fb) {
    int i = blockIdx.x * blockDim.x + threadIdx.x;       // 524288 threads
    const float4* p = reinterpret_cast<const float4*>(f) + (size_t)i * 2;
    float4 a = p[0], b = p[1];
    *reinterpret_cast<bfrag*>(fb + (size_t)i * 8) = pack8(a, b);
}

template<bool BF16F>
__device__ __forceinline__ bfrag load_row8(const float* __restrict__ ff, const short* __restrict__ fb,
                                           int node, int cs) {
    if (BF16F) {
        return *reinterpret_cast<const bfrag*>(fb + node * FF + cs * 8);
    } else {
        const float4* p = reinterpret_cast<const float4*>(ff + node * FF + cs * 8);
        return pack8(p[0], p[1]);
    }
}

// 32 nodes/block, 8 waves. Wave w owns hidden/output cols [16w,16w+16).
// Weights live in unified VGPR/AGPR registers for the whole kernel.
// Deferred-x pipeline: gate partials p = bias + x_{t+1}@Wih^T are computed one
// step ahead, so each step's x-MFMAs are independent of the activation chain
// and fill the matrix pipe while trans/VALU runs.
template<bool BF16F>
__global__ __launch_bounds__(512, 2)
void sage_lstm_kernel(const float* __restrict__ featf, const short* __restrict__ featb,
                      const int* __restrict__ nidx,
                      const short* __restrict__ wihb, const short* __restrict__ whhb,
                      const short* __restrict__ w1b, const short* __restrict__ w2b,
                      const float* __restrict__ biasg, const float* __restrict__ biaso,
                      float* __restrict__ out)
{
    __shared__ short xbuf[2][MB * 128];   // x tiles, bf16, XOR-swizzled (2-ahead ping-pong)
    __shared__ short hbuf[2][MB * 128];   // h tiles, bf16, XOR-swizzled (ping-pong)
    __shared__ int   idx_s[MB * DEG];

    const int tid  = (int)threadIdx.x;
    const int lane = tid & 63;
    const int wave = tid >> 6;
    const int n0   = (int)blockIdx.x * MB;

    const int srow = tid >> 4;                    // staging row 0..31
    const int cs   = tid & 15;                    // staging 8-elem column group

    idx_s[tid]       = nidx[n0 * DEG + tid];
    idx_s[512 + tid] = nidx[n0 * DEG + 512 + tid];
    {   bfrag z; for (int j = 0; j < 8; ++j) z[j] = 0;
        reinterpret_cast<bfrag*>(hbuf[0])[tid] = z; }

    // ---- weight B-fragments: lane holds 8 contiguous k for its column ----
    const int colw = wave * 16 + (lane & 15);
    bfrag wih[4][4], whh[4][4];
#pragma unroll
    for (int g = 0; g < 4; ++g) {
        const short* pih = wihb + (g * 128 + colw) * FF + (lane >> 4) * 8;
        const short* phh = whhb + (g * 128 + colw) * FF + (lane >> 4) * 8;
#pragma unroll
        for (int kt = 0; kt < 4; ++kt) {
            wih[g][kt] = *reinterpret_cast<const bfrag*>(pih + kt * 32);
            whh[g][kt] = *reinterpret_cast<const bfrag*>(phh + kt * 32);
        }
    }
    const float bi = biasg[colw];
    const float bf = biasg[128 + colw];
    const float bg = biasg[256 + colw];
    const float bo = biasg[384 + colw];
    const f32x4 bvi = {bi, bi, bi, bi};
    const f32x4 bvf = {bf, bf, bf, bf};
    const f32x4 bvg = {bg, bg, bg, bg};
    const f32x4 bvo = {bo, bo, bo, bo};

    __syncthreads();   // idx_s + hbuf[0] zeros visible

    // ---- stage x_0 into xbuf[0] ----
    {
        bfrag v = load_row8<BF16F>(featf, featb, idx_s[srow * DEG], cs);
        int sb = (srow * 256 + cs * 16) ^ ((srow & 7) << 4);
        *reinterpret_cast<bfrag*>(reinterpret_cast<char*>(xbuf[0]) + sb) = v;
    }
    __syncthreads();

    const int arow = lane & 15;
    const int asub = (lane >> 4) * 16;
    const int hr0  = (lane >> 4) * 4;
    const int swz  = (arow & 7) << 4;             // same for rt0 and rt1 (16 = 0 mod 8)

    // ---- prologue: partials p = bias + x_0 @ Wih^T ; stage x_1 ----
    f32x4 p0i, p0f, p0g, p0o, p1i, p1f, p1g, p1o;
    {
        char* x0p = reinterpret_cast<char*>(xbuf[0]);
        bfrag xa[4];
#pragma unroll
        for (int kt = 0; kt < 4; ++kt)
            xa[kt] = *reinterpret_cast<const bfrag*>(x0p + ((arow * 256 + kt * 64 + asub) ^ swz));
        p0i = bvi; p0f = bvf; p0g = bvg; p0o = bvo;
#pragma unroll
        for (int kt = 0; kt < 4; ++kt) {
            p0i = __builtin_amdgcn_mfma_f32_16x16x32_bf16(xa[kt], wih[0][kt], p0i, 0, 0, 0);
            p0f = __builtin_amdgcn_mfma_f32_16x16x32_bf16(xa[kt], wih[1][kt], p0f, 0, 0, 0);
            p0g = __builtin_amdgcn_mfma_f32_16x16x32_bf16(xa[kt], wih[2][kt], p0g, 0, 0, 0);
            p0o = __builtin_amdgcn_mfma_f32_16x16x32_bf16(xa[kt], wih[3][kt], p0o, 0, 0, 0);
        }
#pragma unroll
        for (int kt = 0; kt < 4; ++kt)
            xa[kt] = *reinterpret_cast<const bfrag*>(x0p + (((16 + arow) * 256 + kt * 64 + asub) ^ swz));
        p1i = bvi; p1f = bvf; p1g = bvg; p1o = bvo;
#pragma unroll
        for (int kt = 0; kt < 4; ++kt) {
            p1i = __builtin_amdgcn_mfma_f32_16x16x32_bf16(xa[kt], wih[0][kt], p1i, 0, 0, 0);
            p1f = __builtin_amdgcn_mfma_f32_16x16x32_bf16(xa[kt], wih[1][kt], p1f, 0, 0, 0);
            p1g = __builtin_amdgcn_mfma_f32_16x16x32_bf16(xa[kt], wih[2][kt], p1g, 0, 0, 0);
            p1o = __builtin_amdgcn_mfma_f32_16x16x32_bf16(xa[kt], wih[3][kt], p1o, 0, 0, 0);
        }
    }
    {
        bfrag v = load_row8<BF16F>(featf, featb, idx_s[srow * DEG + 1], cs);
        int sb = (srow * 256 + cs * 16) ^ ((srow & 7) << 4);
        *reinterpret_cast<bfrag*>(reinterpret_cast<char*>(xbuf[1]) + sb) = v;
    }
    __syncthreads();   // x_1 visible; xbuf[0] reads done

    f32x4 cs0 = {0.f, 0.f, 0.f, 0.f};
    f32x4 cs1 = {0.f, 0.f, 0.f, 0.f};

#pragma unroll 2
    for (int t = 0; t < DEG; ++t) {
        const int cur = t & 1;
        char* hcur = reinterpret_cast<char*>(hbuf[cur]);
        char* hnxt = reinterpret_cast<char*>(hbuf[cur ^ 1]);
        char* xrd  = reinterpret_cast<char*>(xbuf[cur ^ 1]);   // x_{t+1}
        char* xwr  = reinterpret_cast<char*>(xbuf[cur]);       // gets x_{t+2}

        // global prefetch of x_{t+2} rows: lands at end of step
        bfrag pre2;
        if (t < DEG - 2) pre2 = load_row8<BF16F>(featf, featb, idx_s[srow * DEG + t + 2], cs);

        // ================= rt0 =================
        {
            bfrag ha[4];
#pragma unroll
            for (int kt = 0; kt < 4; ++kt)
                ha[kt] = *reinterpret_cast<const bfrag*>(hcur + ((arow * 256 + kt * 64 + asub) ^ swz));
            f32x4 gi = p0i, gf = p0f, gg = p0g, go = p0o;
#pragma unroll
            for (int kt = 0; kt < 4; ++kt) {
                gi = __builtin_amdgcn_mfma_f32_16x16x32_bf16(ha[kt], whh[0][kt], gi, 0, 0, 0);
                gf = __builtin_amdgcn_mfma_f32_16x16x32_bf16(ha[kt], whh[1][kt], gf, 0, 0, 0);
                gg = __builtin_amdgcn_mfma_f32_16x16x32_bf16(ha[kt], whh[2][kt], gg, 0, 0, 0);
                go = __builtin_amdgcn_mfma_f32_16x16x32_bf16(ha[kt], whh[3][kt], go, 0, 0, 0);
            }
            // next-step x partials (independent of the activation below)
            if (t < DEG - 1) {
                bfrag xn[4];
#pragma unroll
                for (int kt = 0; kt < 4; ++kt)
                    xn[kt] = *reinterpret_cast<const bfrag*>(xrd + ((arow * 256 + kt * 64 + asub) ^ swz));
                p0i = bvi; p0f = bvf; p0g = bvg; p0o = bvo;
#pragma unroll
                for (int kt = 0; kt < 4; ++kt) {
                    p0i = __builtin_amdgcn_mfma_f32_16x16x32_bf16(xn[kt], wih[0][kt], p0i, 0, 0, 0);
                    p0f = __builtin_amdgcn_mfma_f32_16x16x32_bf16(xn[kt], wih[1][kt], p0f, 0, 0, 0);
                    p0g = __builtin_amdgcn_mfma_f32_16x16x32_bf16(xn[kt], wih[2][kt], p0g, 0, 0, 0);
                    p0o = __builtin_amdgcn_mfma_f32_16x16x32_bf16(xn[kt], wih[3][kt], p0o, 0, 0, 0);
                }
            }
#pragma unroll
            for (int r = 0; r < 4; ++r) {
                float iv = fsig(gi[r]);
                float fv = fsig(gf[r]);
                float gv = ftanh(gg[r]);
                float ov = fsig(go[r]);
                float c  = fmaf(fv, cs0[r], iv * gv);
                cs0[r] = c;
                float h  = ov * ftanh(c);
                int hrow = hr0 + r;
                int hb   = (hrow * 256 + colw * 2) ^ ((hrow & 7) << 4);
                *reinterpret_cast<unsigned short*>(hnxt + hb) = b16(h);
            }
        }
        // ================= rt1 =================
        {
            bfrag ha[4];
#pragma unroll
            for (int kt = 0; kt < 4; ++kt)
                ha[kt] = *reinterpret_cast<const bfrag*>(hcur + (((16 + arow) * 256 + kt * 64 + asub) ^ swz));
            f32x4 gi = p1i, gf = p1f, gg = p1g, go = p1o;
#pragma unroll
            for (int kt = 0; kt < 4; ++kt) {
                gi = __builtin_amdgcn_mfma_f32_16x16x32_bf16(ha[kt], whh[0][kt], gi, 0, 0, 0);
                gf = __builtin_amdgcn_mfma_f32_16x16x32_bf16(ha[kt], whh[1][kt], gf, 0, 0, 0);
                gg = __builtin_amdgcn_mfma_f32_16x16x32_bf16(ha[kt], whh[2][kt], gg, 0, 0, 0);
                go = __builtin_amdgcn_mfma_f32_16x16x32_bf16(ha[kt], whh[3][kt], go, 0, 0, 0);
            }
            if (t < DEG - 1) {
                bfrag xn[4];
#pragma unroll
                for (int kt = 0; kt < 4; ++kt)
                    xn[kt] = *reinterpret_cast<const bfrag*>(xrd + (((16 + arow) * 256 + kt * 64 + asub) ^ swz));
                p1i = bvi; p1f = bvf; p1g = bvg; p1o = bvo;
#pragma unroll
                for (int kt = 0; kt < 4; ++kt) {
                    p1i = __builtin_amdgcn_mfma_f32_16x16x32_bf16(xn[kt], wih[0][kt], p1i, 0, 0, 0);
                    p1f = __builtin_amdgcn_mfma_f32_16x16x32_bf16(xn[kt], wih[1][kt], p1f, 0, 0, 0);
                    p1g = __builtin_amdgcn_mfma_f32_16x16x32_bf16(xn[kt], wih[2][kt], p1g, 0, 0, 0);
                    p1o = __builtin_amdgcn_mfma_f32_16x16x32_bf16(xn[kt], wih[3][kt], p1o, 0, 0, 0);
                }
            }
#pragma unroll
            for (int r = 0; r < 4; ++r) {
                float iv = fsig(gi[r]);
                float fv = fsig(gf[r]);
                float gv = ftanh(gg[r]);
                float ov = fsig(go[r]);
                float c  = fmaf(fv, cs1[r], iv * gv);
                cs1[r] = c;
                float h  = ov * ftanh(c);
                int hrow = 16 + hr0 + r;
                int hb   = (hrow * 256 + colw * 2) ^ ((hrow & 7) << 4);
                *reinterpret_cast<unsigned short*>(hnxt + hb) = b16(h);
            }
        }

        if (t < DEG - 2) {
            int sb = (srow * 256 + cs * 16) ^ ((srow & 7) << 4);
            *reinterpret_cast<bfrag*>(xwr + sb) = pre2;
        }
        __syncthreads();
    }

    // ---- epilogue: out = feat@W1^T + (h/32)@W2^T + (b1+b2); h_final in hbuf[0] ----
    {
        bfrag v = load_row8<BF16F>(featf, featb, n0 + srow, cs);
        int sb = (srow * 256 + cs * 16) ^ ((srow & 7) << 4);
        *reinterpret_cast<bfrag*>(reinterpret_cast<char*>(xbuf[0]) + sb) = v;
    }
    __syncthreads();

    bfrag w1f[4], w2f[4];
#pragma unroll
    for (int kt = 0; kt < 4; ++kt) {
        w1f[kt] = *reinterpret_cast<const bfrag*>(w1b + colw * FF + kt * 32 + (lane >> 4) * 8);
        w2f[kt] = *reinterpret_cast<const bfrag*>(w2b + colw * FF + kt * 32 + (lane >> 4) * 8);
    }
    const float bb = biaso[colw];
#pragma unroll
    for (int rt = 0; rt < 2; ++rt) {
        const int rowr = rt * 16 + arow;
        bfrag fa[4], hfa[4];
#pragma unroll
        for (int kt = 0; kt < 4; ++kt) {
            int byte = (rowr * 256 + kt * 64 + asub) ^ swz;
            fa[kt]  = *reinterpret_cast<const bfrag*>(reinterpret_cast<char*>(xbuf[0]) + byte);
            hfa[kt] = *reinterpret_cast<const bfrag*>(reinterpret_cast<char*>(hbuf[0]) + byte);
        }
        f32x4 acc = {0.f, 0.f, 0.f, 0.f};
#pragma unroll
        for (int kt = 0; kt < 4; ++kt) {
            acc = __builtin_amdgcn_mfma_f32_16x16x32_bf16(fa[kt],  w1f[kt], acc, 0, 0, 0);
            acc = __builtin_amdgcn_mfma_f32_16x16x32_bf16(hfa[kt], w2f[kt], acc, 0, 0, 0);
        }
#pragma unroll
        for (int r = 0; r < 4; ++r) {
            int orow = n0 + rt * 16 + hr0 + r;
            out[orow * OO + colw] = acc[r] + bb;
        }
    }
}

extern "C" void kernel_launch(void* const* d_in, const int* in_sizes, int n_in,
                              void* d_out, int out_size, void* d_ws, size_t ws_size,
                              hipStream_t stream)
{
    const float* feat = (const float*)d_in[0];
    const int*   nidx = (const int*)d_in[1];
    const float* W_ih = (const float*)d_in[2];
    const float* W_hh = (const float*)d_in[3];
    const float* b_ih = (const float*)d_in[4];
    const float* b_hh = (const float*)d_in[5];
    const float* W1   = (const float*)d_in[6];
    const float* b1   = (const float*)d_in[7];
    const float* W2   = (const float*)d_in[8];
    const float* b2   = (const float*)d_in[9];
    float* out = (float*)d_out;

    char* ws = (char*)d_ws;
    short* wihb  = (short*)(ws);             // 131072 B
    short* whhb  = (short*)(ws + 131072);    // 131072 B
    short* w1b   = (short*)(ws + 262144);    // 32768 B
    short* w2b   = (short*)(ws + 294912);    // 32768 B
    float* biasg = (float*)(ws + 327680);    // 2048 B
    float* biaso = (float*)(ws + 329728);    // 512 B
    short* featb = (short*)(ws + 330240);    // 8388608 B (16B-aligned)

    const size_t need = 330240 + (size_t)NN * FF * 2;
    const bool bf = ws_size >= need;

    prep_weights<<<256, 256, 0, stream>>>(W_ih, W_hh, b_ih, b_hh, W1, b1, W2, b2,
                                          wihb, whhb, w1b, w2b, biasg, biaso);
    if (bf) {
        prep_feat<<<2048, 256, 0, stream>>>(feat, featb);
        sage_lstm_kernel<true><<<NN / MB, 512, 0, stream>>>(feat, featb, nidx, wihb, whhb,
                                                            w1b, w2b, biasg, biaso, out);
    } else {
        sage_lstm_kernel<false><<<NN / MB, 512, 0, stream>>>(feat, featb, nidx, wihb, whhb,
                                                             w1b, w2b, biasg, biaso, out);
    }
}